// Round 1
// baseline (120.663 us; speedup 1.0000x reference)
//
#include <hip/hip_runtime.h>

// HarmonicConvolutionFilter on MI355X.
// x: [B=4, S=1024, F=512, C=4] f32;  W: [5, K=4, C=4, O=4] f32;  out: [B,S,F,O=4] f32
// out[b,s,f,o] = sum_t sum_k sum_c x_pad[b, s+t-2, f*(k+1), c] * W[t,k,c,o],  k masked if f*(k+1)>=F
//
// Thread = (b, strip of TS=4 s values, f). f innermost -> coalesced float4 I/O.
// 5-tap time window kept in registers (xw[TS+4]) -> ~3.3x fewer gather loads.
// k-loop breaks per-lane; waves hold consecutive f so break is ~wave-uniform.

#define TSB 4      // time strip per thread
#define THALF 2
#define NTAP 5
#define KH 4       // harmonics
#define CIN 4
#define FB 512
#define SB 1024
#define BB 4

__global__ __launch_bounds__(256, 4)
void harmonic_conv_kernel(const float* __restrict__ x,
                          const float* __restrict__ W,
                          float* __restrict__ out) {
    // grid: B * (S/TSB) * (F/256) = 4 * 256 * 2 = 2048 blocks
    const int f      = ((blockIdx.x & 1) << 8) + threadIdx.x;   // 0..511
    const int sc     = (blockIdx.x >> 1) & (SB / TSB - 1);      // 0..255
    const int b      = blockIdx.x >> 9;                         // 0..3
    const int s_base = sc * TSB;

    const float4* xb = (const float4*)x + (size_t)b * SB * FB;

    float4 acc[TSB];
#pragma unroll
    for (int j = 0; j < TSB; ++j) acc[j] = make_float4(0.f, 0.f, 0.f, 0.f);

#pragma unroll 1
    for (int m = 1; m <= KH; ++m) {
        if (f * m >= FB) break;          // per-lane exit; ~uniform within a wave
        const int g = f * m;

        // load the time window for this harmonic into registers
        float4 xw[TSB + 2 * THALF];
#pragma unroll
        for (int r = 0; r < TSB + 2 * THALF; ++r) {
            const int sp = s_base + r - THALF;   // block-uniform predicate
            if (sp >= 0 && sp < SB)
                xw[r] = xb[(size_t)sp * FB + g];
            else
                xw[r] = make_float4(0.f, 0.f, 0.f, 0.f);
        }

        const float* wk = W + (m - 1) * 16;      // W[t][m-1][c][o], c*4+o inner
#pragma unroll
        for (int t = 0; t < NTAP; ++t) {
            const float* wp = wk + t * 64;       // uniform addr -> scalar loads
            float w[16];
#pragma unroll
            for (int i = 0; i < 16; ++i) w[i] = wp[i];
#pragma unroll
            for (int j = 0; j < TSB; ++j) {
                const float4 xv = xw[j + t];
                acc[j].x += xv.x * w[0] + xv.y * w[4] + xv.z * w[8]  + xv.w * w[12];
                acc[j].y += xv.x * w[1] + xv.y * w[5] + xv.z * w[9]  + xv.w * w[13];
                acc[j].z += xv.x * w[2] + xv.y * w[6] + xv.z * w[10] + xv.w * w[14];
                acc[j].w += xv.x * w[3] + xv.y * w[7] + xv.z * w[11] + xv.w * w[15];
            }
        }
    }

    float4* ob = (float4*)out + (size_t)b * SB * FB;
#pragma unroll
    for (int j = 0; j < TSB; ++j)
        ob[(size_t)(s_base + j) * FB + f] = acc[j];
}

extern "C" void kernel_launch(void* const* d_in, const int* in_sizes, int n_in,
                              void* d_out, int out_size, void* d_ws, size_t ws_size,
                              hipStream_t stream) {
    const float* x = (const float*)d_in[0];
    const float* W = (const float*)d_in[1];
    float* out = (float*)d_out;
    const int nblocks = BB * (SB / TSB) * (FB / 256);   // 2048
    harmonic_conv_kernel<<<nblocks, 256, 0, stream>>>(x, W, out);
}

// Round 2
// 95.091 us; speedup vs baseline: 1.2689x; 1.2689x over previous
//
#include <hip/hip_runtime.h>

// HarmonicConvolutionFilter on MI355X (round 2).
// x: [B=4, S=1024, F=512, C=4] f32;  W: [5, K=4, C=4, O=4] f32;  out: [B,S,F,4] f32
// out[b,s,f,o] = sum_t sum_k sum_c x_pad[b,s+t-2, f*(k+1), c] * W[t,k,c,o], k masked if f*(k+1)>=F
//
// Round-2 changes vs round 1 (56 us, FETCH 127MB = 3.8x input):
//  1. Block = (b, s-strip of 4, ALL 512 f): thread tid does f=tid (m=1..4)
//     AND f=tid+256 (m=1 only) -> uniform work per block, no imbalance tail.
//  2. XCD-contiguous swizzle: work=(bid&7)*128+(bid>>3) gives each XCD a
//     contiguous ~4MB (b,s)-chunk == its private L2 -> harmonic/halo re-reads
//     become L2 hits instead of 127MB of L2-miss traffic.

#define TS    4      // time strip per thread
#define NTAP  5
#define FB    512
#define SB    1024
#define BB    4

__global__ __launch_bounds__(256, 4)
void harmonic_conv_kernel(const float* __restrict__ x,
                          const float* __restrict__ W,
                          float* __restrict__ out) {
    // grid: BB * (SB/TS) = 1024 blocks of 256 threads
    const int bid  = blockIdx.x;
    const int work = ((bid & 7) << 7) + (bid >> 3);   // XCD gets contiguous chunk
    const int b    = work >> 8;                       // 0..3
    const int s0   = (work & 255) * TS;               // 0..1020
    const int tid  = threadIdx.x;

    const float4* xb = (const float4*)x + (size_t)b * SB * FB;
    float4*       ob = (float4*)out + (size_t)b * SB * FB;

    // ---------- high half: f = tid + 256, only harmonic m=1 valid ----------
    {
        const int g = tid + 256;
        float4 xw[TS + 4];
#pragma unroll
        for (int r = 0; r < TS + 4; ++r) {
            const int sp = s0 + r - 2;                // block-uniform predicate
            xw[r] = (sp >= 0 && sp < SB) ? xb[(size_t)sp * FB + g]
                                         : make_float4(0.f, 0.f, 0.f, 0.f);
        }
        float4 acc[TS];
#pragma unroll
        for (int j = 0; j < TS; ++j) acc[j] = make_float4(0.f, 0.f, 0.f, 0.f);
#pragma unroll
        for (int t = 0; t < NTAP; ++t) {
            const float* wp = W + t * 64;             // k=0; uniform -> s_load
            float w[16];
#pragma unroll
            for (int i = 0; i < 16; ++i) w[i] = wp[i];
#pragma unroll
            for (int j = 0; j < TS; ++j) {
                const float4 xv = xw[j + t];
                acc[j].x += xv.x*w[0] + xv.y*w[4] + xv.z*w[8]  + xv.w*w[12];
                acc[j].y += xv.x*w[1] + xv.y*w[5] + xv.z*w[9]  + xv.w*w[13];
                acc[j].z += xv.x*w[2] + xv.y*w[6] + xv.z*w[10] + xv.w*w[14];
                acc[j].w += xv.x*w[3] + xv.y*w[7] + xv.z*w[11] + xv.w*w[15];
            }
        }
#pragma unroll
        for (int j = 0; j < TS; ++j)
            ob[(size_t)(s0 + j) * FB + g] = acc[j];
    }

    // ---------- low half: f = tid (0..255), harmonics m=1..4 ----------
    {
        const int f = tid;
        float4 acc[TS];
#pragma unroll
        for (int j = 0; j < TS; ++j) acc[j] = make_float4(0.f, 0.f, 0.f, 0.f);

#pragma unroll
        for (int m = 1; m <= 4; ++m) {
            const int g = f * m;
            if (g < FB) {                             // m=1,2 always true here
                float4 xw[TS + 4];
#pragma unroll
                for (int r = 0; r < TS + 4; ++r) {
                    const int sp = s0 + r - 2;
                    xw[r] = (sp >= 0 && sp < SB) ? xb[(size_t)sp * FB + g]
                                                 : make_float4(0.f, 0.f, 0.f, 0.f);
                }
#pragma unroll
                for (int t = 0; t < NTAP; ++t) {
                    const float* wp = W + t * 64 + (m - 1) * 16;
                    float w[16];
#pragma unroll
                    for (int i = 0; i < 16; ++i) w[i] = wp[i];
#pragma unroll
                    for (int j = 0; j < TS; ++j) {
                        const float4 xv = xw[j + t];
                        acc[j].x += xv.x*w[0] + xv.y*w[4] + xv.z*w[8]  + xv.w*w[12];
                        acc[j].y += xv.x*w[1] + xv.y*w[5] + xv.z*w[9]  + xv.w*w[13];
                        acc[j].z += xv.x*w[2] + xv.y*w[6] + xv.z*w[10] + xv.w*w[14];
                        acc[j].w += xv.x*w[3] + xv.y*w[7] + xv.z*w[11] + xv.w*w[15];
                    }
                }
            }
        }
#pragma unroll
        for (int j = 0; j < TS; ++j)
            ob[(size_t)(s0 + j) * FB + f] = acc[j];
    }
}

extern "C" void kernel_launch(void* const* d_in, const int* in_sizes, int n_in,
                              void* d_out, int out_size, void* d_ws, size_t ws_size,
                              hipStream_t stream) {
    const float* x = (const float*)d_in[0];
    const float* W = (const float*)d_in[1];
    float* out = (float*)d_out;
    const int nblocks = BB * (SB / TS);   // 1024
    harmonic_conv_kernel<<<nblocks, 256, 0, stream>>>(x, W, out);
}